// Round 1
// baseline (1090.576 us; speedup 1.0000x reference)
//
#include <hip/hip_runtime.h>
#include <math.h>

#define B  2
#define S  2048
#define D  1024
#define NH 16
#define HD 64
#define NROWS (B * S)   // 4096

// ---------------------------------------------------------------------------
// GEMM out = x @ W^T (W row-major [D][D], K contiguous in both operands).
// 64x64 tile, BK=16, 256 threads, 4x4 acc per thread.
// mode qkv: epilogue applies RoPE (Q,K) and writes [b][h][s][hd] layout.
// ---------------------------------------------------------------------------
__global__ __launch_bounds__(256) void gemm_qkv_kernel(
    const float* __restrict__ x,
    const float* __restrict__ Wq, const float* __restrict__ Wk,
    const float* __restrict__ Wv,
    float* __restrict__ Qo, float* __restrict__ Ko, float* __restrict__ Vo)
{
    const int mat = blockIdx.z;                       // 0=Q 1=K 2=V
    const float* __restrict__ W = (mat == 0) ? Wq : (mat == 1) ? Wk : Wv;
    float* __restrict__ out     = (mat == 0) ? Qo : (mat == 1) ? Ko : Vo;

    __shared__ float As[16][68];   // [k][m]  (stride 68: 16B-aligned rows, <=2-way conflicts)
    __shared__ float Bs[16][68];   // [k][n]

    const int t  = threadIdx.x;
    const int tx = t & 15, ty = t >> 4;
    const int i0 = blockIdx.x * 64;                   // row tile
    const int j0 = blockIdx.y * 64;                   // col tile

    const int lrow = t >> 2;                          // 0..63
    const int lk   = (t & 3) * 4;                     // 0,4,8,12

    const float* xa = x + (size_t)(i0 + lrow) * D + lk;
    const float* wa = W + (size_t)(j0 + lrow) * D + lk;

    float acc[4][4] = {};

    for (int k0 = 0; k0 < D; k0 += 16) {
        float4 av = *(const float4*)(xa + k0);
        float4 bv = *(const float4*)(wa + k0);
        __syncthreads();
        As[lk + 0][lrow] = av.x; As[lk + 1][lrow] = av.y;
        As[lk + 2][lrow] = av.z; As[lk + 3][lrow] = av.w;
        Bs[lk + 0][lrow] = bv.x; Bs[lk + 1][lrow] = bv.y;
        Bs[lk + 2][lrow] = bv.z; Bs[lk + 3][lrow] = bv.w;
        __syncthreads();
        #pragma unroll
        for (int kk = 0; kk < 16; ++kk) {
            float4 a4 = *(const float4*)&As[kk][ty * 4];
            float4 b4 = *(const float4*)&Bs[kk][tx * 4];
            float a[4] = {a4.x, a4.y, a4.z, a4.w};
            float b[4] = {b4.x, b4.y, b4.z, b4.w};
            #pragma unroll
            for (int i = 0; i < 4; ++i)
                #pragma unroll
                for (int j = 0; j < 4; ++j)
                    acc[i][j] += a[i] * b[j];
        }
    }

    // Epilogue: RoPE for Q,K; store to [b][h][s][hd]
    const int jc0  = j0 + tx * 4;
    const int h    = jc0 >> 6;
    const int dim0 = jc0 & 63;                        // multiple of 4 -> rope pairs local
    #pragma unroll
    for (int i = 0; i < 4; ++i) {
        const int gi  = i0 + ty * 4 + i;
        const int si  = gi & (S - 1);
        const int bb  = gi >> 11;                     // gi / S
        float vals[4];
        if (mat < 2) {
            #pragma unroll
            for (int p = 0; p < 2; ++p) {
                const int de = dim0 + p * 2;          // even dim within head
                float invf = powf(10000.0f, -(float)de / 64.0f);
                float ang  = (float)si * invf;
                float sn, cs;
                sincosf(ang, &sn, &cs);
                float x1 = acc[i][p * 2], x2 = acc[i][p * 2 + 1];
                vals[p * 2]     = x1 * cs - x2 * sn;
                vals[p * 2 + 1] = x1 * sn + x2 * cs;
            }
        } else {
            vals[0] = acc[i][0]; vals[1] = acc[i][1];
            vals[2] = acc[i][2]; vals[3] = acc[i][3];
        }
        float* dst = out + (((size_t)(bb * NH + h) * S + si) * HD + dim0);
        *(float4*)dst = make_float4(vals[0], vals[1], vals[2], vals[3]);
    }
}

// ---------------------------------------------------------------------------
// Plain GEMM out = ctx @ Wo^T, row-major output [NROWS][D].
// ---------------------------------------------------------------------------
__global__ __launch_bounds__(256) void gemm_out_kernel(
    const float* __restrict__ xin, const float* __restrict__ W,
    float* __restrict__ out)
{
    __shared__ float As[16][68];
    __shared__ float Bs[16][68];

    const int t  = threadIdx.x;
    const int tx = t & 15, ty = t >> 4;
    const int i0 = blockIdx.x * 64;
    const int j0 = blockIdx.y * 64;

    const int lrow = t >> 2;
    const int lk   = (t & 3) * 4;

    const float* xa = xin + (size_t)(i0 + lrow) * D + lk;
    const float* wa = W   + (size_t)(j0 + lrow) * D + lk;

    float acc[4][4] = {};

    for (int k0 = 0; k0 < D; k0 += 16) {
        float4 av = *(const float4*)(xa + k0);
        float4 bv = *(const float4*)(wa + k0);
        __syncthreads();
        As[lk + 0][lrow] = av.x; As[lk + 1][lrow] = av.y;
        As[lk + 2][lrow] = av.z; As[lk + 3][lrow] = av.w;
        Bs[lk + 0][lrow] = bv.x; Bs[lk + 1][lrow] = bv.y;
        Bs[lk + 2][lrow] = bv.z; Bs[lk + 3][lrow] = bv.w;
        __syncthreads();
        #pragma unroll
        for (int kk = 0; kk < 16; ++kk) {
            float4 a4 = *(const float4*)&As[kk][ty * 4];
            float4 b4 = *(const float4*)&Bs[kk][tx * 4];
            float a[4] = {a4.x, a4.y, a4.z, a4.w};
            float b[4] = {b4.x, b4.y, b4.z, b4.w};
            #pragma unroll
            for (int i = 0; i < 4; ++i)
                #pragma unroll
                for (int j = 0; j < 4; ++j)
                    acc[i][j] += a[i] * b[j];
        }
    }

    #pragma unroll
    for (int i = 0; i < 4; ++i) {
        const int gi = i0 + ty * 4 + i;
        *(float4*)(out + (size_t)gi * D + j0 + tx * 4) =
            make_float4(acc[i][0], acc[i][1], acc[i][2], acc[i][3]);
    }
}

// ---------------------------------------------------------------------------
// Flash attention, causal. One block = 64 q-rows of one (b,h).
// Q,K staged transposed [d][q]/[d][k]; V [k][d]; P transposed [k][q].
// 256 threads as 16x16; thread (tx,ty) owns S/O sub-tile rows ty*4.., cols tx*4..
// ---------------------------------------------------------------------------
__global__ __launch_bounds__(256) void attn_kernel(
    const float* __restrict__ Q, const float* __restrict__ K,
    const float* __restrict__ V, float* __restrict__ ctx)
{
    __shared__ float Qt[64][68];   // [d][q]
    __shared__ float Kt[64][68];   // [d][k]
    __shared__ float Vs[64][68];   // [k][d]
    __shared__ float Pt[64][68];   // [k][q]

    const int t  = threadIdx.x;
    const int tx = t & 15, ty = t >> 4;
    const int bh = blockIdx.y;                 // bb*NH + h
    const int q0 = blockIdx.x * 64;
    const size_t base = (size_t)bh * S * HD;

    // stage Q tile transposed (once per block)
    {
        const float4* Qg = (const float4*)(Q + base + (size_t)q0 * HD);
        for (int v = t; v < 64 * 16; v += 256) {
            float4 f = Qg[v];
            int row = v >> 4, d0 = (v & 15) << 2;
            Qt[d0 + 0][row] = f.x; Qt[d0 + 1][row] = f.y;
            Qt[d0 + 2][row] = f.z; Qt[d0 + 3][row] = f.w;
        }
    }

    float m[4], l[4], o[4][4];
    #pragma unroll
    for (int i = 0; i < 4; ++i) {
        m[i] = -INFINITY; l[i] = 0.0f;
        #pragma unroll
        for (int j = 0; j < 4; ++j) o[i][j] = 0.0f;
    }

    const int nkt = blockIdx.x;                // process kt = 0..nkt (causal)
    for (int kt = 0; kt <= nkt; ++kt) {
        const int k0 = kt * 64;
        __syncthreads();                       // prev-iter Pt/Kt/Vs reads done
        {
            const float4* Kg = (const float4*)(K + base + (size_t)k0 * HD);
            const float4* Vg = (const float4*)(V + base + (size_t)k0 * HD);
            for (int v = t; v < 64 * 16; v += 256) {
                float4 f = Kg[v];
                int row = v >> 4, d0 = (v & 15) << 2;
                Kt[d0 + 0][row] = f.x; Kt[d0 + 1][row] = f.y;
                Kt[d0 + 2][row] = f.z; Kt[d0 + 3][row] = f.w;
                *(float4*)&Vs[row][d0] = Vg[v];
            }
        }
        __syncthreads();

        // S = Q K^T (outer-product over d)
        float sacc[4][4] = {};
        #pragma unroll 8
        for (int dd = 0; dd < 64; ++dd) {
            float4 a4 = *(const float4*)&Qt[dd][ty * 4];
            float4 b4 = *(const float4*)&Kt[dd][tx * 4];
            float a[4] = {a4.x, a4.y, a4.z, a4.w};
            float b[4] = {b4.x, b4.y, b4.z, b4.w};
            #pragma unroll
            for (int i = 0; i < 4; ++i)
                #pragma unroll
                for (int j = 0; j < 4; ++j)
                    sacc[i][j] += a[i] * b[j];
        }

        const bool diag = (kt == nkt);
        float alpha[4];
        #pragma unroll
        for (int i = 0; i < 4; ++i) {
            const int qg = q0 + ty * 4 + i;
            float vmax = -INFINITY;
            #pragma unroll
            for (int j = 0; j < 4; ++j) {
                float sv = sacc[i][j] * 0.125f;    // 1/sqrt(64)
                if (diag && (k0 + tx * 4 + j > qg)) sv = -INFINITY;
                sacc[i][j] = sv;
                vmax = fmaxf(vmax, sv);
            }
            #pragma unroll
            for (int off = 1; off < 16; off <<= 1)
                vmax = fmaxf(vmax, __shfl_xor(vmax, off));
            float mn = fmaxf(m[i], vmax);
            alpha[i] = expf(m[i] - mn);
            m[i] = mn;
            float ps = 0.0f;
            #pragma unroll
            for (int j = 0; j < 4; ++j) {
                float p = expf(sacc[i][j] - mn);
                sacc[i][j] = p;
                ps += p;
            }
            #pragma unroll
            for (int off = 1; off < 16; off <<= 1)
                ps += __shfl_xor(ps, off);
            l[i] = l[i] * alpha[i] + ps;
            #pragma unroll
            for (int j = 0; j < 4; ++j) o[i][j] *= alpha[i];
        }

        // stage P transposed [k][q]
        #pragma unroll
        for (int i = 0; i < 4; ++i)
            #pragma unroll
            for (int j = 0; j < 4; ++j)
                Pt[tx * 4 + j][ty * 4 + i] = sacc[i][j];
        __syncthreads();

        // O += P V (outer-product over k)
        #pragma unroll 8
        for (int kk = 0; kk < 64; ++kk) {
            float4 a4 = *(const float4*)&Pt[kk][ty * 4];
            float4 b4 = *(const float4*)&Vs[kk][tx * 4];
            float a[4] = {a4.x, a4.y, a4.z, a4.w};
            float b[4] = {b4.x, b4.y, b4.z, b4.w};
            #pragma unroll
            for (int i = 0; i < 4; ++i)
                #pragma unroll
                for (int j = 0; j < 4; ++j)
                    o[i][j] += a[i] * b[j];
        }
    }

    // epilogue: normalize, write ctx [b][s][d]
    const int h  = bh & (NH - 1);
    const int bb = bh >> 4;
    #pragma unroll
    for (int i = 0; i < 4; ++i) {
        float inv = 1.0f / l[i];
        size_t off = ((size_t)bb * S + q0 + ty * 4 + i) * D + h * HD + tx * 4;
        *(float4*)(ctx + off) = make_float4(o[i][0] * inv, o[i][1] * inv,
                                            o[i][2] * inv, o[i][3] * inv);
    }
}

extern "C" void kernel_launch(void* const* d_in, const int* in_sizes, int n_in,
                              void* d_out, int out_size, void* d_ws, size_t ws_size,
                              hipStream_t stream) {
    (void)in_sizes; (void)n_in; (void)out_size; (void)ws_size;
    const float* x  = (const float*)d_in[0];
    const float* Wq = (const float*)d_in[1];
    const float* Wk = (const float*)d_in[2];
    const float* Wv = (const float*)d_in[3];
    const float* Wo = (const float*)d_in[4];
    float* out = (float*)d_out;

    float* w = (float*)d_ws;                   // needs 4 * 16 MB
    float* Q = w;
    float* K = w + (size_t)NROWS * D;
    float* V = w + 2 * (size_t)NROWS * D;
    float* C = w + 3 * (size_t)NROWS * D;

    dim3 g1(NROWS / 64, D / 64, 3);
    gemm_qkv_kernel<<<g1, 256, 0, stream>>>(x, Wq, Wk, Wv, Q, K, V);

    dim3 g2(S / 64, B * NH);
    attn_kernel<<<g2, 256, 0, stream>>>(Q, K, V, C);

    dim3 g3(NROWS / 64, D / 64);
    gemm_out_kernel<<<g3, 256, 0, stream>>>(C, Wo, out);
}

// Round 3
// 652.902 us; speedup vs baseline: 1.6704x; 1.6704x over previous
//
#include <hip/hip_runtime.h>
#include <math.h>

#define B  2
#define S  2048
#define D  1024
#define NH 16
#define HD 64
#define NROWS (B * S)   // 4096

#define AS1 __attribute__((address_space(1)))
#define AS3 __attribute__((address_space(3)))
// async global->LDS, 16B per lane; LDS dest = wave-uniform base + lane*16
#define GLD16(g, l) __builtin_amdgcn_global_load_lds((const AS1 void*)(g), (AS3 void*)(l), 16, 0, 0)

typedef __attribute__((ext_vector_type(8))) short short8;   // 8 bf16
typedef __attribute__((ext_vector_type(4))) float floatx4;

__device__ inline unsigned short f2bf(float f) {
    union { float f; unsigned int u; } v; v.f = f;
    unsigned int u = v.u;
    u += 0x7fffu + ((u >> 16) & 1);     // RNE
    return (unsigned short)(u >> 16);
}

// ---------------------------------------------------------------------------
// fp32 -> bf16 conversion for x and the four weight matrices.
// ---------------------------------------------------------------------------
__global__ __launch_bounds__(256) void cvt_kernel(
    const float* __restrict__ x,  const float* __restrict__ Wq,
    const float* __restrict__ Wk, const float* __restrict__ Wv,
    const float* __restrict__ Wo,
    unsigned short* __restrict__ xb,  unsigned short* __restrict__ wqb,
    unsigned short* __restrict__ wkb, unsigned short* __restrict__ wvb,
    unsigned short* __restrict__ wob)
{
    size_t idx = (size_t)blockIdx.x * 256 + threadIdx.x;
    const float* src; unsigned short* dst; size_t off;
    if (idx < (1u << 20)) { src = x; dst = xb; off = idx << 2; }
    else {
        size_t r = idx - (1u << 20);
        int w = (int)(r >> 18);
        off = (r & ((1u << 18) - 1)) << 2;
        src = (w == 0) ? Wq : (w == 1) ? Wk : (w == 2) ? Wv : Wo;
        dst = (w == 0) ? wqb : (w == 1) ? wkb : (w == 2) ? wvb : wob;
    }
    float4 f = *(const float4*)(src + off);
    ushort4 o;
    o.x = f2bf(f.x); o.y = f2bf(f.y); o.z = f2bf(f.z); o.w = f2bf(f.w);
    *(ushort4*)(dst + off) = o;
}

// ---------------------------------------------------------------------------
// bf16 MFMA GEMM (m97 pattern): out = A @ W^T, A[M][K], W[N][K] both
// K-contiguous bf16. 128x128 tile, BK=32, 256 thr = 4 waves in 2x2, each wave
// 4x4 MFMA tiles of 16x16x32. QKV variant fuses RoPE + [b][h][s][hd] store.
// ---------------------------------------------------------------------------
__global__ __launch_bounds__(256) void gemm_qkv_mfma(
    const unsigned short* __restrict__ xb,
    const unsigned short* __restrict__ wqb,
    const unsigned short* __restrict__ wkb,
    const unsigned short* __restrict__ wvb,
    float* __restrict__ Qo, float* __restrict__ Ko, float* __restrict__ Vo)
{
    __shared__ short As[128 * 32];     // row-major [row][k], NO padding (GLD16)
    __shared__ short Bs[128 * 32];

    const int t    = threadIdx.x;
    const int wave = t >> 6, lane = t & 63;
    const int i0   = blockIdx.x * 128;
    const int by   = blockIdx.y;                 // 0..23
    const int mat  = by >> 3;                    // 0=Q 1=K 2=V
    const int j0   = (by & 7) * 128;             // col tile within the 1024
    const unsigned short* __restrict__ W = (mat == 0) ? wqb : (mat == 1) ? wkb : wvb;
    float* __restrict__ out = (mat == 0) ? Qo : (mat == 1) ? Ko : Vo;

    const int wm = (wave & 1) * 64, wn = (wave >> 1) * 64;
    const int lm = lane & 15, quad = lane >> 4;

    // staging: 512 16B-chunks per matrix; wave w stages segs {2w, 2w+1}
    const int seg0 = wave * 2;
    const int c0   = seg0 * 64 + lane;
    const int row0 = c0 >> 2, ko0 = (c0 & 3) << 3;
    const int c1   = c0 + 64;
    const int row1 = c1 >> 2, ko1 = (c1 & 3) << 3;

    const unsigned short* Abase = xb + (size_t)i0 * D;
    const unsigned short* Bbase = W  + (size_t)j0 * D;

    floatx4 acc[4][4] = {};

    for (int k0 = 0; k0 < D; k0 += 32) {
        __syncthreads();
        GLD16(Abase + (size_t)row0 * D + k0 + ko0, As + seg0 * 512);
        GLD16(Abase + (size_t)row1 * D + k0 + ko1, As + (seg0 + 1) * 512);
        GLD16(Bbase + (size_t)row0 * D + k0 + ko0, Bs + seg0 * 512);
        GLD16(Bbase + (size_t)row1 * D + k0 + ko1, Bs + (seg0 + 1) * 512);
        __syncthreads();

        short8 a[4], b[4];
        #pragma unroll
        for (int mi = 0; mi < 4; ++mi)
            a[mi] = *(const short8*)&As[(wm + mi * 16 + lm) * 32 + quad * 8];
        #pragma unroll
        for (int ni = 0; ni < 4; ++ni)
            b[ni] = *(const short8*)&Bs[(wn + ni * 16 + lm) * 32 + quad * 8];
        #pragma unroll
        for (int mi = 0; mi < 4; ++mi)
            #pragma unroll
            for (int ni = 0; ni < 4; ++ni)
                acc[mi][ni] = __builtin_amdgcn_mfma_f32_16x16x32_bf16(
                    a[mi], b[ni], acc[mi][ni], 0, 0, 0);
    }

    // epilogue: C/D layout col=lm, row=quad*4+r. RoPE for Q,K (pair = lane^1).
    #pragma unroll
    for (int ni = 0; ni < 4; ++ni) {
        const int nw  = j0 + wn + ni * 16 + lm;   // col within 1024
        const int h   = nw >> 6, dim = nw & 63;
        float invf = 0.0f;
        if (mat < 2)
            invf = exp2f(-(float)(dim & ~1) * (13.287712379549449f / 64.0f));
        #pragma unroll
        for (int mi = 0; mi < 4; ++mi) {
            #pragma unroll
            for (int r = 0; r < 4; ++r) {
                const int mg = i0 + wm + mi * 16 + quad * 4 + r;
                const int si = mg & (S - 1), bb = mg >> 11;
                float v = acc[mi][ni][r];
                float res;
                if (mat < 2) {
                    float pv = __shfl_xor(v, 1);
                    float sn, cs;
                    __sincosf((float)si * invf, &sn, &cs);
                    res = (lane & 1) ? (pv * sn + v * cs) : (v * cs - pv * sn);
                } else {
                    res = v;
                }
                out[((size_t)(bb * NH + h) * S + si) * HD + dim] = res;
            }
        }
    }
}

// out = Cb @ Wo^T, fp32 output [NROWS][D]
__global__ __launch_bounds__(256) void gemm_out_mfma(
    const unsigned short* __restrict__ Cb,
    const unsigned short* __restrict__ wob,
    float* __restrict__ out)
{
    __shared__ short As[128 * 32];
    __shared__ short Bs[128 * 32];

    const int t    = threadIdx.x;
    const int wave = t >> 6, lane = t & 63;
    const int i0   = blockIdx.x * 128;
    const int j0   = blockIdx.y * 128;

    const int wm = (wave & 1) * 64, wn = (wave >> 1) * 64;
    const int lm = lane & 15, quad = lane >> 4;

    const int seg0 = wave * 2;
    const int c0   = seg0 * 64 + lane;
    const int row0 = c0 >> 2, ko0 = (c0 & 3) << 3;
    const int c1   = c0 + 64;
    const int row1 = c1 >> 2, ko1 = (c1 & 3) << 3;

    const unsigned short* Abase = Cb  + (size_t)i0 * D;
    const unsigned short* Bbase = wob + (size_t)j0 * D;

    floatx4 acc[4][4] = {};

    for (int k0 = 0; k0 < D; k0 += 32) {
        __syncthreads();
        GLD16(Abase + (size_t)row0 * D + k0 + ko0, As + seg0 * 512);
        GLD16(Abase + (size_t)row1 * D + k0 + ko1, As + (seg0 + 1) * 512);
        GLD16(Bbase + (size_t)row0 * D + k0 + ko0, Bs + seg0 * 512);
        GLD16(Bbase + (size_t)row1 * D + k0 + ko1, Bs + (seg0 + 1) * 512);
        __syncthreads();

        short8 a[4], b[4];
        #pragma unroll
        for (int mi = 0; mi < 4; ++mi)
            a[mi] = *(const short8*)&As[(wm + mi * 16 + lm) * 32 + quad * 8];
        #pragma unroll
        for (int ni = 0; ni < 4; ++ni)
            b[ni] = *(const short8*)&Bs[(wn + ni * 16 + lm) * 32 + quad * 8];
        #pragma unroll
        for (int mi = 0; mi < 4; ++mi)
            #pragma unroll
            for (int ni = 0; ni < 4; ++ni)
                acc[mi][ni] = __builtin_amdgcn_mfma_f32_16x16x32_bf16(
                    a[mi], b[ni], acc[mi][ni], 0, 0, 0);
    }

    #pragma unroll
    for (int ni = 0; ni < 4; ++ni) {
        const int ng = j0 + wn + ni * 16 + lm;
        #pragma unroll
        for (int mi = 0; mi < 4; ++mi) {
            #pragma unroll
            for (int r = 0; r < 4; ++r) {
                const int mg = i0 + wm + mi * 16 + quad * 4 + r;
                out[(size_t)mg * D + ng] = acc[mi][ni][r];
            }
        }
    }
}

// ---------------------------------------------------------------------------
// Flash attention, causal, fp32. One block = 64 q-rows of one (b,h).
// Pt aliased onto Kt (KP) -> 51 KB LDS -> 3 blocks/CU. Heaviest q-tiles
// dispatched first. 1/sqrt(64) folded into Q staging. Output stored bf16.
// ---------------------------------------------------------------------------
__global__ __launch_bounds__(256) void attn_kernel(
    const float* __restrict__ Q, const float* __restrict__ K,
    const float* __restrict__ V, unsigned short* __restrict__ Cb)
{
    __shared__ float Qt[64][68];   // [d][q], pre-scaled by 0.125
    __shared__ float KP[64][68];   // K^T [d][k] during QK; P^T [k][q] during PV
    __shared__ float Vs[64][68];   // [k][d]

    const int t  = threadIdx.x;
    const int tx = t & 15, ty = t >> 4;
    const int bh = blockIdx.y;
    const int qt = (S / 64 - 1) - blockIdx.x;    // heavy tiles first
    const int q0 = qt * 64;
    const size_t base = (size_t)bh * S * HD;

    {
        const float4* Qg = (const float4*)(Q + base + (size_t)q0 * HD);
        for (int v = t; v < 64 * 16; v += 256) {
            float4 f = Qg[v];
            int row = v >> 4, d0 = (v & 15) << 2;
            Qt[d0 + 0][row] = f.x * 0.125f; Qt[d0 + 1][row] = f.y * 0.125f;
            Qt[d0 + 2][row] = f.z * 0.125f; Qt[d0 + 3][row] = f.w * 0.125f;
        }
    }

    float m[4], l[4], o[4][4];
    #pragma unroll
    for (int i = 0; i < 4; ++i) {
        m[i] = -INFINITY; l[i] = 0.0f;
        #pragma unroll
        for (int j = 0; j < 4; ++j) o[i][j] = 0.0f;
    }

    const int nkt = qt;
    for (int kt = 0; kt <= nkt; ++kt) {
        const int k0 = kt * 64;
        __syncthreads();                       // prev PV reads of KP/Vs done
        {
            const float4* Kg = (const float4*)(K + base + (size_t)k0 * HD);
            const float4* Vg = (const float4*)(V + base + (size_t)k0 * HD);
            for (int v = t; v < 64 * 16; v += 256) {
                float4 f = Kg[v];
                int row = v >> 4, d0 = (v & 15) << 2;
                KP[d0 + 0][row] = f.x; KP[d0 + 1][row] = f.y;
                KP[d0 + 2][row] = f.z; KP[d0 + 3][row] = f.w;
                *(float4*)&Vs[row][d0] = Vg[v];
            }
        }
        __syncthreads();

        // S = (Q*0.125) K^T
        float sacc[4][4] = {};
        #pragma unroll 8
        for (int dd = 0; dd < 64; ++dd) {
            float4 a4 = *(const float4*)&Qt[dd][ty * 4];
            float4 b4 = *(const float4*)&KP[dd][tx * 4];
            float a[4] = {a4.x, a4.y, a4.z, a4.w};
            float b[4] = {b4.x, b4.y, b4.z, b4.w};
            #pragma unroll
            for (int i = 0; i < 4; ++i)
                #pragma unroll
                for (int j = 0; j < 4; ++j)
                    sacc[i][j] += a[i] * b[j];
        }

        const bool diag = (kt == nkt);
        float alpha[4];
        #pragma unroll
        for (int i = 0; i < 4; ++i) {
            const int qg = q0 + ty * 4 + i;
            float vmax = -INFINITY;
            #pragma unroll
            for (int j = 0; j < 4; ++j) {
                float sv = sacc[i][j];
                if (diag && (k0 + tx * 4 + j > qg)) sv = -INFINITY;
                sacc[i][j] = sv;
                vmax = fmaxf(vmax, sv);
            }
            #pragma unroll
            for (int off = 1; off < 16; off <<= 1)
                vmax = fmaxf(vmax, __shfl_xor(vmax, off));
            float mn = fmaxf(m[i], vmax);
            alpha[i] = __expf(m[i] - mn);
            m[i] = mn;
            float ps = 0.0f;
            #pragma unroll
            for (int j = 0; j < 4; ++j) {
                float p = __expf(sacc[i][j] - mn);
                sacc[i][j] = p;
                ps += p;
            }
            #pragma unroll
            for (int off = 1; off < 16; off <<= 1)
                ps += __shfl_xor(ps, off);
            l[i] = l[i] * alpha[i] + ps;
            #pragma unroll
            for (int j = 0; j < 4; ++j) o[i][j] *= alpha[i];
        }

        __syncthreads();                       // all QK reads of KP done
        #pragma unroll
        for (int j = 0; j < 4; ++j)            // P^T into KP, float4 rows
            *(float4*)&KP[tx * 4 + j][ty * 4] =
                make_float4(sacc[0][j], sacc[1][j], sacc[2][j], sacc[3][j]);
        __syncthreads();

        // O += P V
        #pragma unroll 8
        for (int kk = 0; kk < 64; ++kk) {
            float4 a4 = *(const float4*)&KP[kk][ty * 4];
            float4 b4 = *(const float4*)&Vs[kk][tx * 4];
            float a[4] = {a4.x, a4.y, a4.z, a4.w};
            float b[4] = {b4.x, b4.y, b4.z, b4.w};
            #pragma unroll
            for (int i = 0; i < 4; ++i)
                #pragma unroll
                for (int j = 0; j < 4; ++j)
                    o[i][j] += a[i] * b[j];
        }
    }

    // epilogue: normalize, store bf16 ctx [b][s][d]
    const int h  = bh & (NH - 1);
    const int bb = bh >> 4;
    #pragma unroll
    for (int i = 0; i < 4; ++i) {
        float inv = 1.0f / l[i];
        size_t off = ((size_t)bb * S + q0 + ty * 4 + i) * D + h * HD + tx * 4;
        ushort4 o4;
        o4.x = f2bf(o[i][0] * inv); o4.y = f2bf(o[i][1] * inv);
        o4.z = f2bf(o[i][2] * inv); o4.w = f2bf(o[i][3] * inv);
        *(ushort4*)(Cb + off) = o4;
    }
}

extern "C" void kernel_launch(void* const* d_in, const int* in_sizes, int n_in,
                              void* d_out, int out_size, void* d_ws, size_t ws_size,
                              hipStream_t stream) {
    (void)in_sizes; (void)n_in; (void)out_size; (void)ws_size;
    const float* x  = (const float*)d_in[0];
    const float* Wq = (const float*)d_in[1];
    const float* Wk = (const float*)d_in[2];
    const float* Wv = (const float*)d_in[3];
    const float* Wo = (const float*)d_in[4];
    float* out = (float*)d_out;

    char* w = (char*)d_ws;
    float* Q            = (float*)(w);                              // 16 MB
    float* K            = (float*)(w + (((size_t)16) << 20));       // 16 MB
    float* V            = (float*)(w + (((size_t)32) << 20));       // 16 MB
    unsigned short* Cb  = (unsigned short*)(w + (((size_t)48) << 20));  // 8 MB
    unsigned short* xb  = (unsigned short*)(w + (((size_t)56) << 20));  // 8 MB
    unsigned short* wqb = (unsigned short*)(w + (((size_t)64) << 20));  // 2 MB
    unsigned short* wkb = (unsigned short*)(w + (((size_t)66) << 20));
    unsigned short* wvb = (unsigned short*)(w + (((size_t)68) << 20));
    unsigned short* wob = (unsigned short*)(w + (((size_t)70) << 20));

    cvt_kernel<<<8192, 256, 0, stream>>>(x, Wq, Wk, Wv, Wo,
                                         xb, wqb, wkb, wvb, wob);

    dim3 g1(NROWS / 128, 24);
    gemm_qkv_mfma<<<g1, 256, 0, stream>>>(xb, wqb, wkb, wvb, Q, K, V);

    dim3 g2(S / 64, B * NH);
    attn_kernel<<<g2, 256, 0, stream>>>(Q, K, V, Cb);

    dim3 g3(NROWS / 128, D / 128);
    gemm_out_mfma<<<g3, 256, 0, stream>>>(Cb, wob, out);
}

// Round 4
// 279.536 us; speedup vs baseline: 3.9014x; 2.3357x over previous
//
#include <hip/hip_runtime.h>
#include <math.h>

#define B  2
#define S  2048
#define D  1024
#define NH 16
#define HD 64
#define NROWS (B * S)   // 4096

#define AS1 __attribute__((address_space(1)))
#define AS3 __attribute__((address_space(3)))
#define GLD16(g, l) __builtin_amdgcn_global_load_lds((const AS1 void*)(g), (AS3 void*)(l), 16, 0, 0)

typedef __attribute__((ext_vector_type(8))) short short8;   // 8 bf16
typedef __attribute__((ext_vector_type(4))) float floatx4;

#define MFMA16(a, b, c) __builtin_amdgcn_mfma_f32_16x16x32_bf16((a), (b), (c), 0, 0, 0)

__device__ inline unsigned short f2bf(float f) {
    union { float f; unsigned int u; } v; v.f = f;
    unsigned int u = v.u;
    u += 0x7fffu + ((u >> 16) & 1);     // RNE
    return (unsigned short)(u >> 16);
}

// ---------------------------------------------------------------------------
// fp32 -> bf16 conversion for x and the four weight matrices.
// ---------------------------------------------------------------------------
__global__ __launch_bounds__(256) void cvt_kernel(
    const float* __restrict__ x,  const float* __restrict__ Wq,
    const float* __restrict__ Wk, const float* __restrict__ Wv,
    const float* __restrict__ Wo,
    unsigned short* __restrict__ xb,  unsigned short* __restrict__ wqb,
    unsigned short* __restrict__ wkb, unsigned short* __restrict__ wvb,
    unsigned short* __restrict__ wob)
{
    size_t idx = (size_t)blockIdx.x * 256 + threadIdx.x;
    const float* src; unsigned short* dst; size_t off;
    if (idx < (1u << 20)) { src = x; dst = xb; off = idx << 2; }
    else {
        size_t r = idx - (1u << 20);
        int w = (int)(r >> 18);
        off = (r & ((1u << 18) - 1)) << 2;
        src = (w == 0) ? Wq : (w == 1) ? Wk : (w == 2) ? Wv : Wo;
        dst = (w == 0) ? wqb : (w == 1) ? wkb : (w == 2) ? wvb : wob;
    }
    float4 f = *(const float4*)(src + off);
    ushort4 o;
    o.x = f2bf(f.x); o.y = f2bf(f.y); o.z = f2bf(f.z); o.w = f2bf(f.w);
    *(ushort4*)(dst + off) = o;
}

// ---------------------------------------------------------------------------
// bf16 MFMA GEMM (m97 pattern): out = A @ W^T. QKV variant: RoPE on Q,K,
// Q pre-scaled by 1/8 (exact), bf16 output in [bh][s][hd] layout.
// ---------------------------------------------------------------------------
__global__ __launch_bounds__(256) void gemm_qkv_mfma(
    const unsigned short* __restrict__ xb,
    const unsigned short* __restrict__ wqb,
    const unsigned short* __restrict__ wkb,
    const unsigned short* __restrict__ wvb,
    unsigned short* __restrict__ Qo, unsigned short* __restrict__ Ko,
    unsigned short* __restrict__ Vo)
{
    __shared__ short As[128 * 32];     // row-major [row][k], NO padding (GLD16)
    __shared__ short Bs[128 * 32];

    const int t    = threadIdx.x;
    const int wave = t >> 6, lane = t & 63;
    const int i0   = blockIdx.x * 128;
    const int by   = blockIdx.y;                 // 0..23
    const int mat  = by >> 3;                    // 0=Q 1=K 2=V
    const int j0   = (by & 7) * 128;
    const unsigned short* __restrict__ W = (mat == 0) ? wqb : (mat == 1) ? wkb : wvb;
    unsigned short* __restrict__ out = (mat == 0) ? Qo : (mat == 1) ? Ko : Vo;

    const int wm = (wave & 1) * 64, wn = (wave >> 1) * 64;
    const int lm = lane & 15, quad = lane >> 4;

    const int seg0 = wave * 2;
    const int c0   = seg0 * 64 + lane;
    const int row0 = c0 >> 2, ko0 = (c0 & 3) << 3;
    const int c1   = c0 + 64;
    const int row1 = c1 >> 2, ko1 = (c1 & 3) << 3;

    const unsigned short* Abase = xb + (size_t)i0 * D;
    const unsigned short* Bbase = W  + (size_t)j0 * D;

    floatx4 acc[4][4] = {};

    for (int k0 = 0; k0 < D; k0 += 32) {
        __syncthreads();
        GLD16(Abase + (size_t)row0 * D + k0 + ko0, As + seg0 * 512);
        GLD16(Abase + (size_t)row1 * D + k0 + ko1, As + (seg0 + 1) * 512);
        GLD16(Bbase + (size_t)row0 * D + k0 + ko0, Bs + seg0 * 512);
        GLD16(Bbase + (size_t)row1 * D + k0 + ko1, Bs + (seg0 + 1) * 512);
        __syncthreads();

        short8 a[4], b[4];
        #pragma unroll
        for (int mi = 0; mi < 4; ++mi)
            a[mi] = *(const short8*)&As[(wm + mi * 16 + lm) * 32 + quad * 8];
        #pragma unroll
        for (int ni = 0; ni < 4; ++ni)
            b[ni] = *(const short8*)&Bs[(wn + ni * 16 + lm) * 32 + quad * 8];
        #pragma unroll
        for (int mi = 0; mi < 4; ++mi)
            #pragma unroll
            for (int ni = 0; ni < 4; ++ni)
                acc[mi][ni] = MFMA16(a[mi], b[ni], acc[mi][ni]);
    }

    // epilogue: C/D layout col=lm, row=quad*4+r. RoPE via lane^1 pairing.
    #pragma unroll
    for (int ni = 0; ni < 4; ++ni) {
        const int nw  = j0 + wn + ni * 16 + lm;
        const int h   = nw >> 6, dim = nw & 63;
        float invf = 0.0f;
        if (mat < 2)
            invf = exp2f(-(float)(dim & ~1) * (13.287712379549449f / 64.0f));
        #pragma unroll
        for (int mi = 0; mi < 4; ++mi) {
            #pragma unroll
            for (int r = 0; r < 4; ++r) {
                const int mg = i0 + wm + mi * 16 + quad * 4 + r;
                const int si = mg & (S - 1), bb = mg >> 11;
                float v = acc[mi][ni][r];
                float res;
                if (mat < 2) {
                    float pv = __shfl_xor(v, 1);
                    float sn, cs;
                    __sincosf((float)si * invf, &sn, &cs);
                    res = (lane & 1) ? (pv * sn + v * cs) : (v * cs - pv * sn);
                    if (mat == 0) res *= 0.125f;   // fold 1/sqrt(64), exact
                } else {
                    res = v;
                }
                out[((size_t)(bb * NH + h) * S + si) * HD + dim] = f2bf(res);
            }
        }
    }
}

// out = Cb @ Wo^T, fp32 output [NROWS][D]
__global__ __launch_bounds__(256) void gemm_out_mfma(
    const unsigned short* __restrict__ Cb,
    const unsigned short* __restrict__ wob,
    float* __restrict__ out)
{
    __shared__ short As[128 * 32];
    __shared__ short Bs[128 * 32];

    const int t    = threadIdx.x;
    const int wave = t >> 6, lane = t & 63;
    const int i0   = blockIdx.x * 128;
    const int j0   = blockIdx.y * 128;

    const int wm = (wave & 1) * 64, wn = (wave >> 1) * 64;
    const int lm = lane & 15, quad = lane >> 4;

    const int seg0 = wave * 2;
    const int c0   = seg0 * 64 + lane;
    const int row0 = c0 >> 2, ko0 = (c0 & 3) << 3;
    const int c1   = c0 + 64;
    const int row1 = c1 >> 2, ko1 = (c1 & 3) << 3;

    const unsigned short* Abase = Cb  + (size_t)i0 * D;
    const unsigned short* Bbase = wob + (size_t)j0 * D;

    floatx4 acc[4][4] = {};

    for (int k0 = 0; k0 < D; k0 += 32) {
        __syncthreads();
        GLD16(Abase + (size_t)row0 * D + k0 + ko0, As + seg0 * 512);
        GLD16(Abase + (size_t)row1 * D + k0 + ko1, As + (seg0 + 1) * 512);
        GLD16(Bbase + (size_t)row0 * D + k0 + ko0, Bs + seg0 * 512);
        GLD16(Bbase + (size_t)row1 * D + k0 + ko1, Bs + (seg0 + 1) * 512);
        __syncthreads();

        short8 a[4], b[4];
        #pragma unroll
        for (int mi = 0; mi < 4; ++mi)
            a[mi] = *(const short8*)&As[(wm + mi * 16 + lm) * 32 + quad * 8];
        #pragma unroll
        for (int ni = 0; ni < 4; ++ni)
            b[ni] = *(const short8*)&Bs[(wn + ni * 16 + lm) * 32 + quad * 8];
        #pragma unroll
        for (int mi = 0; mi < 4; ++mi)
            #pragma unroll
            for (int ni = 0; ni < 4; ++ni)
                acc[mi][ni] = MFMA16(a[mi], b[ni], acc[mi][ni]);
    }

    #pragma unroll
    for (int ni = 0; ni < 4; ++ni) {
        const int ng = j0 + wn + ni * 16 + lm;
        #pragma unroll
        for (int mi = 0; mi < 4; ++mi) {
            #pragma unroll
            for (int r = 0; r < 4; ++r) {
                const int mg = i0 + wm + mi * 16 + quad * 4 + r;
                out[(size_t)mg * D + ng] = acc[mi][ni][r];
            }
        }
    }
}

// ---------------------------------------------------------------------------
// V transpose: Vb [bh][s][64] bf16 -> Vt [bh][64][S] bf16. One block per
// (bh, 64-row s-tile). LDS stride 72 (16B-aligned rows, 2-way reads).
// ---------------------------------------------------------------------------
__global__ __launch_bounds__(256) void vtrans_kernel(
    const unsigned short* __restrict__ Vb, unsigned short* __restrict__ Vt)
{
    __shared__ unsigned short T[64][72];
    const int t  = threadIdx.x;
    const int st = blockIdx.x, bh = blockIdx.y;
    const unsigned short* src = Vb + ((size_t)bh * S + st * 64) * HD;

    #pragma unroll
    for (int i = 0; i < 2; ++i) {
        int c = t + i * 256;                 // s = c&63 (lane), dp = c>>6
        int s = c & 63, dp = c >> 6;
        short8 v = *(const short8*)(src + (size_t)s * HD + dp * 8);
        #pragma unroll
        for (int j = 0; j < 8; ++j)
            T[dp * 8 + j][s] = (unsigned short)v[j];   // conflict-free writes
    }
    __syncthreads();
    unsigned short* dst = Vt + (size_t)bh * HD * S + (size_t)st * 64;
    #pragma unroll
    for (int i = 0; i < 2; ++i) {
        int c = t + i * 256;
        int d = c >> 3, sp = (c & 7) * 8;
        short8 v = *(const short8*)&T[d][sp];
        *(short8*)(dst + (size_t)d * S + sp) = v;
    }
}

// ---------------------------------------------------------------------------
// MFMA flash attention, causal. Block = (bh, 64 q-rows); 4 waves, wave w owns
// q-strip [16w,16w+16). All tiles half-split [kf][row][32] for GLD16 +
// conflict-free ds_read_b128. P round-trips LDS (C-layout -> A-layout).
// ---------------------------------------------------------------------------
__global__ __launch_bounds__(256) void attn_mfma(
    const unsigned short* __restrict__ Qb,   // [bh][s][64], pre-scaled 1/8
    const unsigned short* __restrict__ Kb,   // [bh][s][64]
    const unsigned short* __restrict__ Vt,   // [bh][64][S]
    unsigned short* __restrict__ Cb)         // [b][s][1024] bf16
{
    __shared__ unsigned short Qs[2][64][32];
    __shared__ unsigned short Ks[2][64][32];
    __shared__ unsigned short Vs[2][64][32];   // rows = d, cols = k
    __shared__ unsigned short Ps[64][72];      // [q][k]

    const int t    = threadIdx.x;
    const int lane = t & 63, wave = t >> 6;
    const int lm   = lane & 15, quad = lane >> 4;
    const int bh   = blockIdx.y;
    const int qt   = (S / 64 - 1) - blockIdx.x;   // heavy tiles first
    const int q0   = qt * 64;

    const unsigned short* Qg = Qb + (size_t)bh * S * HD;
    const unsigned short* Kg = Kb + (size_t)bh * S * HD;
    const unsigned short* Vg = Vt + (size_t)bh * HD * S;

    // stage Q tile once (512 chunks, 2/thread)
    #pragma unroll
    for (int i = 0; i < 2; ++i) {
        int c = t + i * 256;
        int kf = c >> 8, wi = c & 255, row = wi >> 2, part = wi & 3;
        GLD16(Qg + (size_t)(q0 + row) * HD + kf * 32 + part * 8,
              &Qs[kf][row][part * 8]);
    }
    __syncthreads();
    short8 qa0 = *(const short8*)&Qs[0][16 * wave + lm][quad * 8];
    short8 qa1 = *(const short8*)&Qs[1][16 * wave + lm][quad * 8];

    float m[4], l[4];
    floatx4 o[4] = {};
    #pragma unroll
    for (int r = 0; r < 4; ++r) { m[r] = -INFINITY; l[r] = 0.0f; }

    for (int kt = 0; kt <= qt; ++kt) {
        const int k0 = kt * 64;
        __syncthreads();                       // prior Ks/Vs/Ps reads done
        #pragma unroll
        for (int i = 0; i < 2; ++i) {
            int c = t + i * 256;
            int kf = c >> 8, wi = c & 255, row = wi >> 2, part = wi & 3;
            GLD16(Kg + (size_t)(k0 + row) * HD + kf * 32 + part * 8,
                  &Ks[kf][row][part * 8]);
            GLD16(Vg + (size_t)row * S + k0 + kf * 32 + part * 8,
                  &Vs[kf][row][part * 8]);
        }
        __syncthreads();

        // S-tile: wave strip 16q x 64k, 4 n-tiles x 2 mfma
        floatx4 sc[4];
        #pragma unroll
        for (int nt = 0; nt < 4; ++nt) {
            short8 b0 = *(const short8*)&Ks[0][nt * 16 + lm][quad * 8];
            short8 b1 = *(const short8*)&Ks[1][nt * 16 + lm][quad * 8];
            floatx4 s = {0.f, 0.f, 0.f, 0.f};
            s = MFMA16(qa0, b0, s);
            s = MFMA16(qa1, b1, s);
            sc[nt] = s;
        }

        // online softmax: C-layout rows q=16w+quad*4+r, cols k=nt*16+lm
        const bool diag = (kt == qt);
        #pragma unroll
        for (int r = 0; r < 4; ++r) {
            const int qrow = 16 * wave + quad * 4 + r;
            float mx = -INFINITY;
            #pragma unroll
            for (int nt = 0; nt < 4; ++nt) {
                float v = sc[nt][r];
                if (diag && (nt * 16 + lm > qrow)) v = -INFINITY;
                sc[nt][r] = v;
                mx = fmaxf(mx, v);
            }
            #pragma unroll
            for (int off = 1; off < 16; off <<= 1)
                mx = fmaxf(mx, __shfl_xor(mx, off));
            float mn = fmaxf(m[r], mx);
            float alpha = __expf(m[r] - mn);
            m[r] = mn;
            float ps = 0.0f;
            #pragma unroll
            for (int nt = 0; nt < 4; ++nt) {
                float p = __expf(sc[nt][r] - mn);
                sc[nt][r] = p;
                ps += p;
            }
            #pragma unroll
            for (int off = 1; off < 16; off <<= 1)
                ps += __shfl_xor(ps, off);
            l[r] = l[r] * alpha + ps;
            #pragma unroll
            for (int nt = 0; nt < 4; ++nt) o[nt][r] *= alpha;
        }

        // P -> LDS [q][k] bf16
        #pragma unroll
        for (int nt = 0; nt < 4; ++nt)
            #pragma unroll
            for (int r = 0; r < 4; ++r)
                Ps[16 * wave + quad * 4 + r][nt * 16 + lm] = f2bf(sc[nt][r]);
        __syncthreads();

        // O += P V  (A = P rows, B = Vt rows)
        short8 pa0 = *(const short8*)&Ps[16 * wave + lm][quad * 8];
        short8 pa1 = *(const short8*)&Ps[16 * wave + lm][32 + quad * 8];
        #pragma unroll
        for (int nt = 0; nt < 4; ++nt) {
            short8 vb0 = *(const short8*)&Vs[0][nt * 16 + lm][quad * 8];
            short8 vb1 = *(const short8*)&Vs[1][nt * 16 + lm][quad * 8];
            o[nt] = MFMA16(pa0, vb0, o[nt]);
            o[nt] = MFMA16(pa1, vb1, o[nt]);
        }
    }

    // epilogue: normalize, store bf16 ctx [b][s][d_model]
    const int h = bh & (NH - 1), bb = bh >> 4;
    #pragma unroll
    for (int r = 0; r < 4; ++r) {
        float inv = 1.0f / l[r];
        size_t row = (size_t)bb * S + q0 + 16 * wave + quad * 4 + r;
        #pragma unroll
        for (int nt = 0; nt < 4; ++nt)
            Cb[row * D + h * HD + nt * 16 + lm] = f2bf(o[nt][r] * inv);
    }
}

extern "C" void kernel_launch(void* const* d_in, const int* in_sizes, int n_in,
                              void* d_out, int out_size, void* d_ws, size_t ws_size,
                              hipStream_t stream) {
    (void)in_sizes; (void)n_in; (void)out_size; (void)ws_size;
    const float* x  = (const float*)d_in[0];
    const float* Wq = (const float*)d_in[1];
    const float* Wk = (const float*)d_in[2];
    const float* Wv = (const float*)d_in[3];
    const float* Wo = (const float*)d_in[4];
    float* out = (float*)d_out;

    char* w = (char*)d_ws;
    unsigned short* Qb  = (unsigned short*)(w);                              // 8 MB
    unsigned short* Kb  = (unsigned short*)(w + (((size_t)8)  << 20));       // 8 MB
    unsigned short* Vb  = (unsigned short*)(w + (((size_t)16) << 20));       // 8 MB
    unsigned short* Vtb = (unsigned short*)(w + (((size_t)24) << 20));       // 8 MB
    unsigned short* Cb  = (unsigned short*)(w + (((size_t)32) << 20));       // 8 MB
    unsigned short* xb  = (unsigned short*)(w + (((size_t)40) << 20));       // 8 MB
    unsigned short* wqb = (unsigned short*)(w + (((size_t)48) << 20));       // 2 MB
    unsigned short* wkb = (unsigned short*)(w + (((size_t)50) << 20));
    unsigned short* wvb = (unsigned short*)(w + (((size_t)52) << 20));
    unsigned short* wob = (unsigned short*)(w + (((size_t)54) << 20));

    cvt_kernel<<<8192, 256, 0, stream>>>(x, Wq, Wk, Wv, Wo,
                                         xb, wqb, wkb, wvb, wob);

    dim3 g1(NROWS / 128, 24);
    gemm_qkv_mfma<<<g1, 256, 0, stream>>>(xb, wqb, wkb, wvb, Qb, Kb, Vb);

    dim3 gt(S / 64, B * NH);
    vtrans_kernel<<<gt, 256, 0, stream>>>(Vb, Vtb);

    dim3 g2(S / 64, B * NH);
    attn_mfma<<<g2, 256, 0, stream>>>(Qb, Kb, Vtb, Cb);

    dim3 g3(NROWS / 128, D / 128);
    gemm_out_mfma<<<g3, 256, 0, stream>>>(Cb, wob, out);
}